// Round 6
// baseline (603.898 us; speedup 1.0000x reference)
//
#include <hip/hip_runtime.h>

// B=256, S=512, I=H=O=256, L=64. fp32 in/out; bf16 MFMA internally.
// Operand-swapped MFMA everywhere: D = mfma(W_frag, a_frag) = D[hidden][batch].
// k2_full = encoder + (y0,inj) + decoder + OUTPUT GEMM in one kernel (64 wgs x 512 thr):
//   - alast stays in LDS; inj stays in registers; astate goes to this wg's own
//     consumed xpre slots (slot i*64+bg); epilogue re-reads them (same-CU L2,
//     after vmcnt(0)+barrier) and emits out with k3_out's exact MFMA order.
// k1: 256 wgs x 512 thr, 2 timesteps per wg (wave-groups), 1 occupancy round.
// dup-4 recurrence structure: 4 batch rows/wg, 8 waves (2/SIMD) x 32 hidden cols,
// B-operand 4x column-duplicated -> 2 tanh values/lane, b32 state writes.
typedef unsigned short u16;
typedef unsigned int   u32;
typedef __attribute__((ext_vector_type(8))) __bf16 bf16x8;
typedef __attribute__((ext_vector_type(8))) u16    u16x8;
typedef __attribute__((ext_vector_type(4))) float  f32x4;
typedef __attribute__((ext_vector_type(4))) u32    u32x4;
typedef __attribute__((ext_vector_type(2))) u32    u32x2;

#define MFMA16(a,b,c) __builtin_amdgcn_mfma_f32_16x16x32_bf16((a),(b),(c),0,0,0)
#define C_TANH 2.8853900817779268f   /* 2*log2(e): tanh(v)=1-2/(2^(C*v)+1) */
#define NL2E  -1.4426950408889634f   /* -log2(e): sigm(u)=1/(1+2^(NL2E*u)) */

__device__ __forceinline__ float ubit(u32 x){ return __builtin_bit_cast(float, x); }
__device__ __forceinline__ u16 f2b(float f){ // RNE f32->bf16 (prep paths)
    u32 b = __builtin_bit_cast(u32, f);
    b += 0x7FFFu + ((b >> 16) & 1u);
    return (u16)(b >> 16);
}
__device__ __forceinline__ u32 pkbf(float a, float b){ return ((u32)f2b(b) << 16) | (u32)f2b(a); }
__device__ __forceinline__ u32 pk_away(float a, float b){ // round-away pack (state path)
    u32 ua = (__builtin_bit_cast(u32, a) + 0x8000u) >> 16;
    u32 ub = (__builtin_bit_cast(u32, b) + 0x8000u) & 0xFFFF0000u;
    return ub | ua;
}
// Barrier that drains ONLY LDS counters -- vmem (prefetch/stores) stays in flight.
__device__ __forceinline__ void bar_lds(){ __asm__ volatile("s_waitcnt lgkmcnt(0)\n\ts_barrier" ::: "memory"); }

// ---------------- K1: xpre = C*(x@W1x + b1x + b1a), dup-4 slot order, 2 t per wg ----------------
// slot (8 bf16 = [nt1=0: r0..3][nt1=1: r0..3]) at u16 addr (((t*64+bg)*8 + w8)*16 + q*4 + b4)*8
__global__ __launch_bounds__(512, 2) void k1_xw(const float* __restrict__ x, const float* __restrict__ w1x,
                                               const float* __restrict__ b1x, const float* __restrict__ b1a,
                                               u16* __restrict__ xpre)
{
    const int tid = threadIdx.x, lane = tid & 63;
    const int w8 = tid >> 6;                       // 0..7
    const int wg2 = w8 >> 2, w = w8 & 3;           // wave-group (timestep), col-wave
    const int t = blockIdx.x * 2 + wg2;
    const int l15 = lane & 15, q = lane >> 4;
    const int cw = w * 64;

    bf16x8 bw[4][8];
    f32x4 biasv[4];
    #pragma unroll
    for (int nt = 0; nt < 4; ++nt){
        const int n0 = cw + nt * 16 + q * 4;
        f32x4 bx = *(const f32x4*)(b1x + n0);
        f32x4 ba = *(const f32x4*)(b1a + n0);
        biasv[nt] = (bx + ba) * C_TANH;
        const int n = cw + nt * 16 + l15;
        #pragma unroll
        for (int ks = 0; ks < 8; ++ks){
            u16x8 tt;
            #pragma unroll
            for (int j = 0; j < 8; ++j) tt[j] = f2b(w1x[(ks * 32 + q * 8 + j) * 256 + n] * C_TANH);
            bw[nt][ks] = __builtin_bit_cast(bf16x8, tt);
        }
    }

    for (int blk = 0; blk < 16; ++blk){
        const int b0r = blk * 16;
        bf16x8 av[8];
        #pragma unroll
        for (int ks = 0; ks < 8; ++ks){
            const float* p = x + ((size_t)(b0r + l15) * 512 + t) * 256 + ks * 32 + q * 8;
            f32x4 v0 = *(const f32x4*)p;
            f32x4 v1 = *(const f32x4*)(p + 4);
            u32x4 dd = { pkbf(v0[0], v0[1]), pkbf(v0[2], v0[3]),
                         pkbf(v1[0], v1[1]), pkbf(v1[2], v1[3]) };
            av[ks] = __builtin_bit_cast(bf16x8, dd);
        }
        f32x4 acc[4];
        #pragma unroll
        for (int nt = 0; nt < 4; ++nt) acc[nt] = biasv[nt];
        #pragma unroll
        for (int ks = 0; ks < 8; ++ks)
            #pragma unroll
            for (int nt = 0; nt < 4; ++nt)
                acc[nt] = MFMA16(bw[nt][ks], av[ks], acc[nt]);   // swapped: D[hidden][batch]
        const int bg = blk * 4 + (l15 >> 2), b4 = l15 & 3;
        #pragma unroll
        for (int p2 = 0; p2 < 2; ++p2){
            const size_t a16 = ((((size_t)t * 64 + bg) * 8 + (w * 2 + p2)) * 16 + q * 4 + b4) * 8;
            u32x4 V = { pkbf(acc[p2 * 2][0], acc[p2 * 2][1]), pkbf(acc[p2 * 2][2], acc[p2 * 2][3]),
                        pkbf(acc[p2 * 2 + 1][0], acc[p2 * 2 + 1][1]), pkbf(acc[p2 * 2 + 1][2], acc[p2 * 2 + 1][3]) };
            *(u32x4*)(xpre + a16) = V;
        }
    }
}

// ---------------- K2_full: encoder + y0/inj + decoder + out GEMM, 64 wgs x 512 thr ----------------
__global__ __launch_bounds__(512, 2) void k2_full(const float* __restrict__ w1a, const float* __restrict__ wy,
                                                 const float* __restrict__ by,  const float* __restrict__ w2x,
                                                 const float* __restrict__ w2a, const float* __restrict__ b2x,
                                                 const float* __restrict__ b2a, u16* ws,
                                                 float* __restrict__ out)
{
    __shared__ __align__(16) u16 st[2][4][272];
    const int tid = threadIdx.x, lane = tid & 63, w = tid >> 6;   // w 0..7, 32 hidden cols each
    const int l15 = lane & 15, q = lane >> 4;
    const int b4 = l15 & 3;
    const bool selnt = (l15 & 4) != 0, selrp = (l15 & 8) != 0;
    const int wcol = w * 32 + (selnt ? 16 : 0) + q * 4 + (selrp ? 2 : 0);
    const int bg = blockIdx.x;                     // 0..63, batches bg*4 .. bg*4+3

    bf16x8 bw[2][8];                               // C-scaled W1a as A-operand (32 cols), reg-resident
    #pragma unroll
    for (int nt = 0; nt < 2; ++nt){
        const int n = w * 32 + nt * 16 + l15;
        #pragma unroll
        for (int ks = 0; ks < 8; ++ks){
            u16x8 tt;
            #pragma unroll
            for (int j = 0; j < 8; ++j) tt[j] = f2b(w1a[(ks * 32 + q * 8 + j) * 256 + n] * C_TANH);
            bw[nt][ks] = __builtin_bit_cast(bf16x8, tt);
        }
    }
    for (int i = tid; i < 4 * 272; i += 512) (&st[0][0][0])[i] = 0;   // a0 = 0
    __syncthreads();

    // per-lane xpre slot: 8 bf16 = one dwordx4 per step (dup across l15>>2 groups)
    const u16* xp = ws + (((size_t)bg * 8 + w) * 16 + q * 4 + b4) * 8;
    u32x4 c = *(const u32x4*)xp;
    u32x4 a = *(const u32x4*)(xp + 65536);

    const u16 (*sR)[272] = st[0];
    u16 (*sW)[272] = st[1];

    // ============ Phase E: encoder, 512 steps ============
    for (int t = 0; t < 512; ++t){
        const size_t tp = (size_t)((t + 2 < 512) ? t + 2 : 511) * 65536;
        u32x4 n_ = *(const u32x4*)(xp + tp);

        bf16x8 av[8];                              // B-operand: a[batch=b4][k]; 4-way broadcast
        #pragma unroll
        for (int ks = 0; ks < 8; ++ks)
            av[ks] = *(const bf16x8*)&sR[b4][ks * 32 + q * 8];

        f32x4 acc[2];                              // init = scaled xpre (identical across dup groups)
        #pragma unroll
        for (int nt = 0; nt < 2; ++nt)
            #pragma unroll
            for (int r = 0; r < 4; ++r){
                const u32 d = c[nt * 2 + (r >> 1)];
                acc[nt][r] = ubit((r & 1) ? (d & 0xFFFF0000u) : (d << 16));
            }
        __builtin_amdgcn_s_setprio(1);
        #pragma unroll
        for (int ks = 0; ks < 8; ++ks)
            #pragma unroll
            for (int nt = 0; nt < 2; ++nt)
                acc[nt] = MFMA16(bw[nt][ks], av[ks], acc[nt]);   // swapped
        __builtin_amdgcn_s_setprio(0);

        // each lane handles 2 real values: nt by l15 bit2, r-pair by bit3
        const float s0 = selnt ? acc[1][0] : acc[0][0];
        const float s1 = selnt ? acc[1][1] : acc[0][1];
        const float s2 = selnt ? acc[1][2] : acc[0][2];
        const float s3 = selnt ? acc[1][3] : acc[0][3];
        const float mv0 = selrp ? s2 : s0;
        const float mv1 = selrp ? s3 : s1;
        const float e0 = __builtin_amdgcn_exp2f(mv0);
        const float t0 = 1.0f - 2.0f * __builtin_amdgcn_rcpf(e0 + 1.0f);
        const float e1 = __builtin_amdgcn_exp2f(mv1);
        const float t1 = 1.0f - 2.0f * __builtin_amdgcn_rcpf(e1 + 1.0f);
        *(u32*)&sW[b4][wcol] = pk_away(t0, t1);

        c = a; a = n_;
        bar_lds();                                   // LDS-only drain; vmem stays in flight
        const u16 (*tmp)[272] = sR; sR = (const u16(*)[272])sW; sW = (u16(*)[272])tmp;
    }
    // sR now holds alast (4 batches x 256 bf16) in LDS.

    // ============ Phase P: y0 = sigm(alast@Wy+by); inj = C*(y0@W2x) in regs ============
    bf16x8 bwy[2][8];                              // NL2E-scaled Wy -- kept live for the epilogue
    f32x4 biasy[2];
    #pragma unroll
    for (int nt = 0; nt < 2; ++nt){
        const int n0 = w * 32 + nt * 16 + q * 4;
        biasy[nt] = (*(const f32x4*)(by + n0)) * NL2E;
        const int n = w * 32 + nt * 16 + l15;
        #pragma unroll
        for (int ks = 0; ks < 8; ++ks){
            u16x8 tt;
            #pragma unroll
            for (int j = 0; j < 8; ++j) tt[j] = f2b(wy[(ks * 32 + q * 8 + j) * 256 + n] * NL2E);
            bwy[nt][ks] = __builtin_bit_cast(bf16x8, tt);
        }
    }
    {
        bf16x8 av[8];
        #pragma unroll
        for (int ks = 0; ks < 8; ++ks) av[ks] = *(const bf16x8*)&sR[b4][ks * 32 + q * 8];
        f32x4 acc[2];
        #pragma unroll
        for (int nt = 0; nt < 2; ++nt) acc[nt] = biasy[nt];
        #pragma unroll
        for (int ks = 0; ks < 8; ++ks)
            #pragma unroll
            for (int nt = 0; nt < 2; ++nt) acc[nt] = MFMA16(bwy[nt][ks], av[ks], acc[nt]);
        const float s0 = selnt ? acc[1][0] : acc[0][0];
        const float s1 = selnt ? acc[1][1] : acc[0][1];
        const float s2 = selnt ? acc[1][2] : acc[0][2];
        const float s3 = selnt ? acc[1][3] : acc[0][3];
        const float mv0 = selrp ? s2 : s0;
        const float mv1 = selrp ? s3 : s1;
        const float y0v = __builtin_amdgcn_rcpf(1.0f + __builtin_amdgcn_exp2f(mv0));
        const float y1v = __builtin_amdgcn_rcpf(1.0f + __builtin_amdgcn_exp2f(mv1));
        *(u32*)&sW[b4][wcol] = pkbf(y0v, y1v);     // y0 into the free buffer
    }
    bar_lds();

    f32x4 ini[2];                                  // decoder i==0 init, stays in registers
    f32x4 bias2[2];
    {
        bf16x8 av2[8];
        #pragma unroll
        for (int ks = 0; ks < 8; ++ks) av2[ks] = *(const bf16x8*)&sW[b4][ks * 32 + q * 8];
        bar_lds();                                 // all y0 reads done; decoder may overwrite sW
        #pragma unroll
        for (int nt = 0; nt < 2; ++nt){
            const int n0 = w * 32 + nt * 16 + q * 4;
            f32x4 bx = *(const f32x4*)(b2x + n0);
            f32x4 ba = *(const f32x4*)(b2a + n0);
            bias2[nt] = (bx + ba) * C_TANH;
            ini[nt] = (f32x4){0.f, 0.f, 0.f, 0.f};
        }
        #pragma unroll
        for (int ks = 0; ks < 8; ++ks)
            #pragma unroll
            for (int nt = 0; nt < 2; ++nt){
                const int n = w * 32 + nt * 16 + l15;
                u16x8 tt;
                #pragma unroll
                for (int j = 0; j < 8; ++j) tt[j] = f2b(w2x[(ks * 32 + q * 8 + j) * 256 + n] * C_TANH);
                ini[nt] = MFMA16(__builtin_bit_cast(bf16x8, tt), av2[ks], ini[nt]);
            }
        #pragma unroll
        for (int nt = 0; nt < 2; ++nt) ini[nt] = ini[nt] + bias2[nt];
        // re-prep bw with C-scaled W2a (encoder weights dead)
        #pragma unroll
        for (int nt = 0; nt < 2; ++nt){
            const int n = w * 32 + nt * 16 + l15;
            #pragma unroll
            for (int ks = 0; ks < 8; ++ks){
                u16x8 tt;
                #pragma unroll
                for (int j = 0; j < 8; ++j) tt[j] = f2b(w2a[(ks * 32 + q * 8 + j) * 256 + n] * C_TANH);
                bw[nt][ks] = __builtin_bit_cast(bf16x8, tt);
            }
        }
    }

    // ============ Phase D: decoder, 64 steps; astate into own consumed xpre slots ============
    for (int i = 0; i < 64; ++i){
        bf16x8 av[8];
        #pragma unroll
        for (int ks = 0; ks < 8; ++ks) av[ks] = *(const bf16x8*)&sR[b4][ks * 32 + q * 8];
        f32x4 acc[2];
        #pragma unroll
        for (int nt = 0; nt < 2; ++nt) acc[nt] = ini[nt];
        __builtin_amdgcn_s_setprio(1);
        #pragma unroll
        for (int ks = 0; ks < 8; ++ks)
            #pragma unroll
            for (int nt = 0; nt < 2; ++nt) acc[nt] = MFMA16(bw[nt][ks], av[ks], acc[nt]);
        __builtin_amdgcn_s_setprio(0);

        const float s0 = selnt ? acc[1][0] : acc[0][0];
        const float s1 = selnt ? acc[1][1] : acc[0][1];
        const float s2 = selnt ? acc[1][2] : acc[0][2];
        const float s3 = selnt ? acc[1][3] : acc[0][3];
        const float mv0 = selrp ? s2 : s0;
        const float mv1 = selrp ? s3 : s1;
        const float e0 = __builtin_amdgcn_exp2f(mv0);
        const float t0 = 1.0f - 2.0f * __builtin_amdgcn_rcpf(e0 + 1.0f);
        const float e1 = __builtin_amdgcn_exp2f(mv1);
        const float t1 = 1.0f - 2.0f * __builtin_amdgcn_rcpf(e1 + 1.0f);
        const u32 hp = pk_away(t0, t1);
        *(u32*)&sW[b4][wcol] = hp;
        // astate slot (i*64+bg): owned by this wg, consumed by its encoder long ago
        *(u32*)(ws + (((size_t)(i * 64 + bg)) << 10) + b4 * 256 + wcol) = hp;

        if (i == 0){
            #pragma unroll
            for (int nt = 0; nt < 2; ++nt) ini[nt] = bias2[nt];
        }
        bar_lds();
        const u16 (*tmp)[272] = sR; sR = (const u16(*)[272])sW; sW = (u16(*)[272])tmp;
    }

    // ============ Phase O: out = sigm(astate@Wy + by) for this wg's 4 batches ============
    __asm__ volatile("s_waitcnt vmcnt(0)" ::: "memory");   // drain own astate stores
    __syncthreads();                                        // all waves' stores in L2
    const int ib4 = l15 & 3;                                // batch-in-wg for this lane's row
    const int ri4 = l15 >> 2;                               // i sub-index within row tile
    for (int rt = 0; rt < 16; ++rt){
        const int ii = rt * 4 + ri4;                        // 0..63
        const u16* ap = ws + (((size_t)(ii * 64 + bg)) << 10) + (size_t)ib4 * 256;
        bf16x8 av[8];
        #pragma unroll
        for (int ks = 0; ks < 8; ++ks)
            av[ks] = *(const bf16x8*)(ap + ks * 32 + q * 8);
        f32x4 acc[2];
        #pragma unroll
        for (int nt = 0; nt < 2; ++nt) acc[nt] = biasy[nt];
        __builtin_amdgcn_s_setprio(1);
        #pragma unroll
        for (int ks = 0; ks < 8; ++ks)
            #pragma unroll
            for (int nt = 0; nt < 2; ++nt) acc[nt] = MFMA16(bwy[nt][ks], av[ks], acc[nt]);
        __builtin_amdgcn_s_setprio(0);
        const int bL = bg * 4 + ib4;
        #pragma unroll
        for (int nt = 0; nt < 2; ++nt){
            f32x4 o4;
            #pragma unroll
            for (int r = 0; r < 4; ++r)
                o4[r] = __builtin_amdgcn_rcpf(1.0f + __builtin_amdgcn_exp2f(acc[nt][r]));
            *(f32x4*)(out + ((size_t)bL * 64 + ii) * 256 + w * 32 + nt * 16 + q * 4) = o4;
        }
    }
}

extern "C" void kernel_launch(void* const* d_in, const int* in_sizes, int n_in,
                              void* d_out, int out_size, void* d_ws, size_t ws_size,
                              hipStream_t stream) {
    const float* x   = (const float*)d_in[0];
    const float* w1x = (const float*)d_in[1];
    const float* b1x = (const float*)d_in[2];
    const float* w1a = (const float*)d_in[3];
    const float* b1a = (const float*)d_in[4];
    const float* w2x = (const float*)d_in[5];
    const float* b2x = (const float*)d_in[6];
    const float* w2a = (const float*)d_in[7];
    const float* b2a = (const float*)d_in[8];
    const float* wy  = (const float*)d_in[9];
    const float* by  = (const float*)d_in[10];

    u16*   ws16 = (u16*)d_ws;       // 64 MiB xpre; decoder reuses per-wg consumed slots for astate
    float* o    = (float*)d_out;

    k1_xw  <<<256, 512, 0, stream>>>(x, w1x, b1x, b1a, ws16);
    k2_full<<<64,  512, 0, stream>>>(w1a, wy, by, w2x, w2a, b2x, b2a, ws16, o);
}